// Round 6
// baseline (531.744 us; speedup 1.0000x reference)
//
#include <hip/hip_runtime.h>

typedef unsigned short u16;
typedef __attribute__((ext_vector_type(8))) short short8;
typedef __attribute__((ext_vector_type(4))) short short4v;
typedef __attribute__((ext_vector_type(2))) unsigned uint2v;
typedef __attribute__((ext_vector_type(4))) float floatx4;

#define NB 64
#define HH 56
#define WW_ 56
#define CC 128
#define NHEADS 4
#define WS2 49
#define PAD 4      // P_T = P_L = 4
#define HID 512

__device__ __forceinline__ float bf2f(u16 u){ return __uint_as_float(((unsigned)u)<<16); }
__device__ __forceinline__ u16 f2bf(float f){
  unsigned u = __float_as_uint(f);
  return (u16)((u + 0x7FFFu + ((u>>16)&1u)) >> 16);
}
// pack two f32 -> one u32 of 2 bf16 (lo = a, hi = b)
__device__ __forceinline__ unsigned pk2(float a, float b){
  return ((unsigned)f2bf(b) << 16) | (unsigned)f2bf(a);
}
// RNE pack via HW cvt; 2 instrs vs 14 manual
__device__ __forceinline__ short4v pk4(float a, float b, float c, float d){
  unsigned w0, w1;
  asm("v_cvt_pk_bf16_f32 %0, %1, %2" : "=v"(w0) : "v"(a), "v"(b));
  asm("v_cvt_pk_bf16_f32 %0, %1, %2" : "=v"(w1) : "v"(c), "v"(d));
  uint2v u; u[0] = w0; u[1] = w1;
  return __builtin_bit_cast(short4v, u);
}
// tanh-approx GELU, sigmoid form, approx rcp (1-instr) instead of precise div
__device__ __forceinline__ float gelu_f(float x){
  float u2 = x*(1.5957691216f + 0.0713548162f*x*x);
  return x * __builtin_amdgcn_rcpf(1.f + __expf(-u2));
}
// element-wise fragment load (LDS); compiler merges to widest aligned DS op
__device__ __forceinline__ short8 ld_frag(const u16* p){
  short8 v;
  #pragma unroll
  for (int e = 0; e < 8; e++) v[e] = (short)p[e];
  return v;
}
__device__ __forceinline__ short4v ld_frag4(const u16* p){
  short4v v;
  #pragma unroll
  for (int e = 0; e < 4; e++) v[e] = (short)p[e];
  return v;
}
// vector fragment load (global, 16B-aligned)
__device__ __forceinline__ short8 ld_frag_g(const u16* p){
  return *(const short8*)p;
}
// concat two 4-element halves into an 8-element fragment
__device__ __forceinline__ short8 cat8(short4v lo, short4v hi){
  short8 v;
  #pragma unroll
  for (int e = 0; e < 4; e++) { v[e] = lo[e]; v[e+4] = hi[e]; }
  return v;
}

// ---------------------------------------------------------------------------
// prep: fc1_w (C,HID) f32 -> bf16 [HID][C];  fc2_w (HID,C) f32 -> bf16 [C][HID]
//       spatial_w [h][i][j] f32 -> bf16 [h][i(64)][j(stride 80)], zero-padded
//       (stride 80 u16 = 160 B -> rows 16B-aligned => global b128 frag loads)
// ---------------------------------------------------------------------------
__global__ __launch_bounds__(256) void prep_k(
    const float* __restrict__ fc1_w, const float* __restrict__ fc2_w,
    const float* __restrict__ sw,
    u16* __restrict__ fc1_wT, u16* __restrict__ fc2_wT, u16* __restrict__ swT)
{
  int tid = blockIdx.x*256 + threadIdx.x;
  int nth = gridDim.x * 256;
  for (int idx = tid; idx < HID*CC; idx += nth) {
    int n = idx >> 7, k = idx & 127;
    fc1_wT[idx] = f2bf(fc1_w[k*HID + n]);
  }
  for (int idx = tid; idx < CC*HID; idx += nth) {
    int c = idx >> 9, h = idx & 511;
    fc2_wT[idx] = f2bf(fc2_w[h*CC + c]);
  }
  for (int idx = tid; idx < NHEADS*64*80; idx += nth) {
    int hd = idx / (64*80); int rem = idx - hd*64*80;
    int i = rem / 80, j = rem - i*80;
    swT[idx] = (i < WS2 && j < WS2) ? f2bf(sw[(hd*WS2 + i)*WS2 + j]) : (u16)0;
  }
}

// ---------------------------------------------------------------------------
// winmix v3: fused LN1 + shifted-window token mix (MFMA) + residual -> x2
// one block per (batch, window); wave = head.
// W is 40 KB, L2-hot, identical for all 5184 blocks -> read A-frags DIRECT
// from global (no LDS staging, no stage barrier). LDS = xnt only (16.9 KB),
// ONE barrier, launch_bounds(256,4) -> ~6 blocks/CU (latency-bound kernel).
// ---------------------------------------------------------------------------
__global__ __launch_bounds__(256, 4) void winmix_k(
    const float* __restrict__ x, const float* __restrict__ g1, const float* __restrict__ b1,
    const u16* __restrict__ swT, const float* __restrict__ sb,
    float* __restrict__ x2)
{
  __shared__ u16 xnt[CC*66];         // 16896 B, bf16 LN-out [c][j] stride 66
  int tid = threadIdx.x;
  int wvid = tid >> 6, lane = tid & 63;
  int ln = lane & 15, qd = lane >> 4;
  int b = blockIdx.x / 81; int wi = blockIdx.x - b*81;
  int wh = wi / 9, wwn = wi - wh*9;
  int hd = wvid;

  // W A-frags straight from global (L2-hot); no deps -> hoisted under LN
  short8 af[4][2];
  #pragma unroll
  for (int mt = 0; mt < 4; mt++)
    #pragma unroll
    for (int ks = 0; ks < 2; ks++)
      af[mt][ks] = ld_frag_g(&swT[(size_t)(hd*64 + mt*16 + ln)*80 + ks*32 + qd*8]);

  // LN per window position (transposed write), float2-vectorized; jj>=49 -> 0
  float2 gl = *(const float2*)&g1[2*lane];
  float2 bl = *(const float2*)&b1[2*lane];
  for (int jj = wvid; jj < 64; jj += 4) {
    u16 o0 = 0, o1 = 0;
    if (jj < WS2) {
      int jr = jj / 7, jc = jj - jr*7;
      int pr = wh*7 + jr - PAD, pc = wwn*7 + jc - PAD;
      bool valid = (pr>=0) & (pr<HH) & (pc>=0) & (pc<WW_);
      float2 v = {0.f, 0.f};
      const float* px = x + ((size_t)((b*HH + pr)*WW_ + pc))*CC;
      if (valid) v = *(const float2*)(px + 2*lane);
      float s = v.x + v.y, ss = v.x*v.x + v.y*v.y;
      #pragma unroll
      for (int o = 32; o > 0; o >>= 1) { s += __shfl_xor(s, o); ss += __shfl_xor(ss, o); }
      float mu = s * (1.f/128.f);
      float var = ss * (1.f/128.f) - mu*mu;
      float rs = rsqrtf(var + 1e-5f);
      if (valid) {
        o0 = f2bf((v.x - mu)*rs*gl.x + bl.x);
        o1 = f2bf((v.y - mu)*rs*gl.y + bl.y);
      }
    }
    xnt[(2*lane  )*66 + jj] = o0;
    xnt[(2*lane+1)*66 + jj] = o1;
  }
  __syncthreads();

  // MFMA token mix: wave = head
  short8 bf_[2][2];
  #pragma unroll
  for (int nt = 0; nt < 2; nt++)
    #pragma unroll
    for (int ks = 0; ks < 2; ks++)
      bf_[nt][ks] = ld_frag(&xnt[(hd*32 + nt*16 + ln)*66 + ks*32 + qd*8]);
  floatx4 acc[4][2];
  #pragma unroll
  for (int mt = 0; mt < 4; mt++)
    #pragma unroll
    for (int nt = 0; nt < 2; nt++)
      acc[mt][nt] = (floatx4){0.f,0.f,0.f,0.f};
  #pragma unroll
  for (int ks = 0; ks < 2; ks++)
    #pragma unroll
    for (int mt = 0; mt < 4; mt++)
      #pragma unroll
      for (int nt = 0; nt < 2; nt++)
        acc[mt][nt] = __builtin_amdgcn_mfma_f32_16x16x32_bf16(af[mt][ks], bf_[nt][ks], acc[mt][nt], 0, 0, 0);

  // epilogue: residual add + spatial bias (global, L2-hot) + write
  #pragma unroll
  for (int mt = 0; mt < 4; mt++) {
    #pragma unroll
    for (int r = 0; r < 4; r++) {
      int i = mt*16 + qd*4 + r;
      if (i < WS2) {
        int ir = i / 7, ic = i - ir*7;
        int orow = wh*7 + ir - PAD, ocol = wwn*7 + ic - PAD;
        if (orow>=0 && orow<HH && ocol>=0 && ocol<WW_) {
          float sbv = sb[hd*WS2 + i];
          size_t base = ((size_t)((b*HH + orow)*WW_ + ocol))*CC + hd*32;
          #pragma unroll
          for (int nt = 0; nt < 2; nt++) {
            int c = nt*16 + ln;
            x2[base + c] = x[base + c] + acc[mt][nt][r] + sbv;
          }
        }
      }
    }
  }
}

// ---------------------------------------------------------------------------
// mlp v7: x2 -> LN2 -> fc1+GELU -> fc2 -> +x2 (in-place, f32 I/O, bf16 MFMA)
// v2's proven staging pipeline (cooperative LDS weights, register prefetch,
// 2-barrier/chunk, launch_bounds(256,2) -- (256,3) spills the prefetch
// payload, +255 MB HBM writes, v5), with the Ht LDS round-trip removed via a
// k-slot PERMUTATION (no 16x16x16 builtin exists on gfx950 -- v6):
//  - gemm1 swapped: lane (ln,qd) gets D'[hid=kt*16+qd*4+r][tok=ln].
//  - two kt sub-tiles (32 hid) pack PER-LANE into one 16x16x32 B-frag with
//    k-slot(qd,e) <-> hid = 32kb + 16*(e>>2) + qd*4 + (e&3).
//  - W2 A-frag read from B2p with the SAME permutation: two b64 loads at
//    row*72 + kb*32 + {0,16} + qd*4 (bank 4ln+2qd mod 32 = 2 lanes/bank).
//  - gemm2 = proven mfma_f32_16x16x32_bf16; zero cross-lane ops, no Ht LDS.
//  - O^T accumulators -> float4 residual RMW epilogue.
// LDS 35840 B (ALn union B1p|B2p).
// ---------------------------------------------------------------------------
__global__ __launch_bounds__(256, 2) void mlp_k(
    float* __restrict__ xio,
    const float* __restrict__ g2, const float* __restrict__ b2,
    const u16* __restrict__ fc1_wT, const float* __restrict__ fc1_b,
    const u16* __restrict__ fc2_wT, const float* __restrict__ fc2_b)
{
  // phase A: ALn u16[128][136] (34816 B)
  // phase B: B1p u16[64][136] @0 (17408) | B2p u16[128][72] @17408 (18432)
  //          -> union = 35840 B
  __shared__ __align__(16) char um[35840];
  u16* ALn = (u16*)um;
  u16* B1p = (u16*)um;
  u16* B2p = (u16*)(um + 17408);
  int tid = threadIdx.x;
  int wvid = tid >> 6, lane = tid & 63;
  int ln = lane & 15, qd = lane >> 4;
  int m0 = wvid*32;
  size_t tokbase = (size_t)blockIdx.x * 128;

  // weight staging machinery (register prefetch, one chunk ahead)
  const uint4* src1 = (const uint4*)fc1_wT;   // row = 128 u16 = 16 uint4
  const uint4* src2 = (const uint4*)fc2_wT;   // row = 512 u16 = 64 uint4
  uint4 p1[4], p2[4];
  int n1[4], q1[4], n2[4], q2[4];
  #pragma unroll
  for (int r = 0; r < 4; r++) {
    int idx = tid + r*256;
    n1[r] = idx >> 4; q1[r] = idx & 15;
    n2[r] = idx >> 3; q2[r] = idx & 7;
  }
  auto load_ch = [&](int cc){
    #pragma unroll
    for (int r = 0; r < 4; r++) {
      p1[r] = src1[(cc*64 + n1[r])*16 + q1[r]];
      p2[r] = src2[n2[r]*64 + cc*8 + q2[r]];
    }
  };
  auto store_ch = [&](){
    uint4* d1 = (uint4*)B1p; uint4* d2 = (uint4*)B2p;
    #pragma unroll
    for (int r = 0; r < 4; r++) {
      d1[n1[r]*17 + q1[r]] = p1[r];   // 136 u16 = 17 uint4
      d2[n2[r]*9  + q2[r]] = p2[r];   // 72 u16 = 9 uint4
    }
  };
  load_ch(0);                         // chunk-0 weight fetch overlaps LN2

  // LN2 into ALn (128 tokens, cooperative), float2-vectorized
  float2 gl = *(const float2*)&g2[2*lane];
  float2 bl = *(const float2*)&b2[2*lane];
  for (int t = wvid; t < 128; t += 4) {
    float2 v = *(const float2*)(xio + (tokbase + t)*CC + 2*lane);
    float s = v.x + v.y, ss = v.x*v.x + v.y*v.y;
    #pragma unroll
    for (int o = 32; o > 0; o >>= 1) { s += __shfl_xor(s,o); ss += __shfl_xor(ss,o); }
    float mu = s*(1.f/128.f), var = ss*(1.f/128.f) - mu*mu;
    float rs = rsqrtf(var + 1e-5f);
    *(unsigned*)&ALn[t*136 + 2*lane] =
        pk2((v.x-mu)*rs*gl.x + bl.x, (v.y-mu)*rs*gl.y + bl.y);
  }
  __syncthreads();

  // token B-frags to VGPRs (ALn dead afterwards)
  short8 bv[2][4];
  #pragma unroll
  for (int n = 0; n < 2; n++)
    #pragma unroll
    for (int ks = 0; ks < 4; ks++)
      bv[n][ks] = ld_frag(&ALn[(m0 + n*16 + ln)*136 + ks*32 + qd*8]);
  __syncthreads();

  store_ch();
  __syncthreads();

  floatx4 oacc[8][2];                 // O^T: [c-tile][tok-half]
  #pragma unroll
  for (int nt = 0; nt < 8; nt++)
    #pragma unroll
    for (int th = 0; th < 2; th++) oacc[nt][th] = (floatx4){0.f,0.f,0.f,0.f};

  for (int ch = 0; ch < 8; ch++) {
    if (ch < 7) load_ch(ch+1);        // prefetch next chunk into VGPRs

    #pragma unroll
    for (int kb = 0; kb < 2; ++kb) {  // 32-hid block = one gemm2 K-step
      short4v pkv[2][2];              // [kt-in-pair][tok-half]
      #pragma unroll
      for (int kp = 0; kp < 2; ++kp) {
        int kt = kb*2 + kp;
        // gemm1 (swapped): D'[16 hid][tok], A = W1 rows (B1p), B = bv (VGPR)
        short8 aw[4];
        #pragma unroll
        for (int ks = 0; ks < 4; ks++)
          aw[ks] = ld_frag(&B1p[(kt*16 + ln)*136 + ks*32 + qd*8]);
        floatx4 h0 = (floatx4){0.f,0.f,0.f,0.f};
        floatx4 h1 = (floatx4){0.f,0.f,0.f,0.f};
        #pragma unroll
        for (int ks = 0; ks < 4; ks++) {
          h0 = __builtin_amdgcn_mfma_f32_16x16x32_bf16(aw[ks], bv[0][ks], h0, 0, 0, 0);
          h1 = __builtin_amdgcn_mfma_f32_16x16x32_bf16(aw[ks], bv[1][ks], h1, 0, 0, 0);
        }
        // lane holds hid = ch*64+kt*16+qd*4+r for tok = th*16+ln
        floatx4 bias = *(const floatx4*)&fc1_b[ch*64 + kt*16 + qd*4];
        pkv[kp][0] = pk4(gelu_f(h0[0]+bias[0]), gelu_f(h0[1]+bias[1]),
                         gelu_f(h0[2]+bias[2]), gelu_f(h0[3]+bias[3]));
        pkv[kp][1] = pk4(gelu_f(h1[0]+bias[0]), gelu_f(h1[1]+bias[1]),
                         gelu_f(h1[2]+bias[2]), gelu_f(h1[3]+bias[3]));
      }
      // per-lane k-slot pack: e=0..3 <- kt even, e=4..7 <- kt odd
      short8 g0 = cat8(pkv[0][0], pkv[1][0]);
      short8 g1 = cat8(pkv[0][1], pkv[1][1]);
      // gemm2: O^T[c][tok] += W2-perm @ G-pack (16x16x32, k = 32 hid)
      #pragma unroll
      for (int nt = 0; nt < 8; nt++) {
        const u16* wrow = &B2p[(nt*16 + ln)*72 + kb*32 + qd*4];
        short8 aw2 = cat8(ld_frag4(wrow), ld_frag4(wrow + 16));
        oacc[nt][0] = __builtin_amdgcn_mfma_f32_16x16x32_bf16(aw2, g0, oacc[nt][0], 0, 0, 0);
        oacc[nt][1] = __builtin_amdgcn_mfma_f32_16x16x32_bf16(aw2, g1, oacc[nt][1], 0, 0, 0);
      }
    }
    __syncthreads();                  // all waves done reading B1/B2
    if (ch < 7) { store_ch(); __syncthreads(); }
  }

  // epilogue: + fc2 bias + residual, in-place, float4 RMW
  #pragma unroll
  for (int nt = 0; nt < 8; nt++) {
    floatx4 bias = *(const floatx4*)&fc2_b[nt*16 + qd*4];
    #pragma unroll
    for (int th = 0; th < 2; th++) {
      size_t tok = tokbase + m0 + th*16 + ln;
      float* rp = xio + tok*CC + nt*16 + qd*4;
      floatx4 v = *(floatx4*)rp;
      v = v + oacc[nt][th] + bias;
      *(floatx4*)rp = v;
    }
  }
}

extern "C" void kernel_launch(void* const* d_in, const int* in_sizes, int n_in,
                              void* d_out, int out_size, void* d_ws, size_t ws_size,
                              hipStream_t stream) {
  const float* x     = (const float*)d_in[0];
  const float* g1    = (const float*)d_in[1];
  const float* b1    = (const float*)d_in[2];
  const float* sw    = (const float*)d_in[3];
  const float* sb    = (const float*)d_in[4];
  const float* g2    = (const float*)d_in[5];
  const float* b2    = (const float*)d_in[6];
  const float* fc1_w = (const float*)d_in[7];
  const float* fc1_b = (const float*)d_in[8];
  const float* fc2_w = (const float*)d_in[9];
  const float* fc2_b = (const float*)d_in[10];
  float* out = (float*)d_out;

  u16* fc1_wT = (u16*)d_ws;                  // 512*128 bf16 (131072 B)
  u16* fc2_wT = fc1_wT + HID*CC;             // 128*512 bf16 (131072 B)
  u16* swT    = fc2_wT + CC*HID;             // 4*64*80 bf16 (40960 B)

  prep_k<<<64, 256, 0, stream>>>(fc1_w, fc2_w, sw, fc1_wT, fc2_wT, swT);
  winmix_k<<<NB*81, 256, 0, stream>>>(x, g1, b1, swT, sb, out);
  mlp_k<<<(NB*HH*WW_)/128, 256, 0, stream>>>(out, g2, b2, fc1_wT, fc1_b, fc2_wT, fc2_b);
}

// Round 7
// 459.876 us; speedup vs baseline: 1.1563x; 1.1563x over previous
//
#include <hip/hip_runtime.h>

typedef unsigned short u16;
typedef __attribute__((ext_vector_type(8))) short short8;
typedef __attribute__((ext_vector_type(4))) float floatx4;

#define NB 64
#define HH 56
#define WW_ 56
#define CC 128
#define NHEADS 4
#define WS2 49
#define PAD 4      // P_T = P_L = 4
#define HID 512

__device__ __forceinline__ float bf2f(u16 u){ return __uint_as_float(((unsigned)u)<<16); }
__device__ __forceinline__ u16 f2bf(float f){
  unsigned u = __float_as_uint(f);
  return (u16)((u + 0x7FFFu + ((u>>16)&1u)) >> 16);
}
// pack two f32 -> one u32 of 2 bf16 (lo = a, hi = b)
__device__ __forceinline__ unsigned pk2(float a, float b){
  return ((unsigned)f2bf(b) << 16) | (unsigned)f2bf(a);
}
// tanh-approx GELU, sigmoid form, approx rcp (validated v6/v7, absmax unchanged)
__device__ __forceinline__ float gelu_f(float x){
  float u2 = x*(1.5957691216f + 0.0713548162f*x*x);
  return x * __builtin_amdgcn_rcpf(1.f + __expf(-u2));
}
// element-wise fragment load (LDS); compiler merges to widest aligned DS op
__device__ __forceinline__ short8 ld_frag(const u16* p){
  short8 v;
  #pragma unroll
  for (int e = 0; e < 8; e++) v[e] = (short)p[e];
  return v;
}
// vector fragment load (global, 16B-aligned)
__device__ __forceinline__ short8 ld_frag_g(const u16* p){
  return *(const short8*)p;
}

// ---------------------------------------------------------------------------
// prep: fc1_w (C,HID) f32 -> bf16 [HID][C];  fc2_w (HID,C) f32 -> bf16 [C][HID]
//       spatial_w [h][i][j] f32 -> bf16 [h][i(64)][j(stride 80)], zero-padded
//       (stride 80 u16 = 160 B -> rows 16B-aligned => global b128 frag loads)
// ---------------------------------------------------------------------------
__global__ __launch_bounds__(256) void prep_k(
    const float* __restrict__ fc1_w, const float* __restrict__ fc2_w,
    const float* __restrict__ sw,
    u16* __restrict__ fc1_wT, u16* __restrict__ fc2_wT, u16* __restrict__ swT)
{
  int tid = blockIdx.x*256 + threadIdx.x;
  int nth = gridDim.x * 256;
  for (int idx = tid; idx < HID*CC; idx += nth) {
    int n = idx >> 7, k = idx & 127;
    fc1_wT[idx] = f2bf(fc1_w[k*HID + n]);
  }
  for (int idx = tid; idx < CC*HID; idx += nth) {
    int c = idx >> 9, h = idx & 511;
    fc2_wT[idx] = f2bf(fc2_w[h*CC + c]);
  }
  for (int idx = tid; idx < NHEADS*64*80; idx += nth) {
    int hd = idx / (64*80); int rem = idx - hd*64*80;
    int i = rem / 80, j = rem - i*80;
    swT[idx] = (i < WS2 && j < WS2) ? f2bf(sw[(hd*WS2 + i)*WS2 + j]) : (u16)0;
  }
}

// ---------------------------------------------------------------------------
// winmix v3 (proven round 6): fused LN1 + window token mix + residual -> x2
// one block per (batch, window); wave = head. W read DIRECT from global
// (L2-hot, 40 KB shared by all 5184 blocks); LDS = xnt only (16.9 KB),
// ONE barrier, launch_bounds(256,4).
// ---------------------------------------------------------------------------
__global__ __launch_bounds__(256, 4) void winmix_k(
    const float* __restrict__ x, const float* __restrict__ g1, const float* __restrict__ b1,
    const u16* __restrict__ swT, const float* __restrict__ sb,
    float* __restrict__ x2)
{
  __shared__ u16 xnt[CC*66];         // 16896 B, bf16 LN-out [c][j] stride 66
  int tid = threadIdx.x;
  int wvid = tid >> 6, lane = tid & 63;
  int ln = lane & 15, qd = lane >> 4;
  int b = blockIdx.x / 81; int wi = blockIdx.x - b*81;
  int wh = wi / 9, wwn = wi - wh*9;
  int hd = wvid;

  // W A-frags straight from global (L2-hot); no deps -> hoisted under LN
  short8 af[4][2];
  #pragma unroll
  for (int mt = 0; mt < 4; mt++)
    #pragma unroll
    for (int ks = 0; ks < 2; ks++)
      af[mt][ks] = ld_frag_g(&swT[(size_t)(hd*64 + mt*16 + ln)*80 + ks*32 + qd*8]);

  // LN per window position (transposed write), float2-vectorized; jj>=49 -> 0
  float2 gl = *(const float2*)&g1[2*lane];
  float2 bl = *(const float2*)&b1[2*lane];
  for (int jj = wvid; jj < 64; jj += 4) {
    u16 o0 = 0, o1 = 0;
    if (jj < WS2) {
      int jr = jj / 7, jc = jj - jr*7;
      int pr = wh*7 + jr - PAD, pc = wwn*7 + jc - PAD;
      bool valid = (pr>=0) & (pr<HH) & (pc>=0) & (pc<WW_);
      float2 v = {0.f, 0.f};
      const float* px = x + ((size_t)((b*HH + pr)*WW_ + pc))*CC;
      if (valid) v = *(const float2*)(px + 2*lane);
      float s = v.x + v.y, ss = v.x*v.x + v.y*v.y;
      #pragma unroll
      for (int o = 32; o > 0; o >>= 1) { s += __shfl_xor(s, o); ss += __shfl_xor(ss, o); }
      float mu = s * (1.f/128.f);
      float var = ss * (1.f/128.f) - mu*mu;
      float rs = rsqrtf(var + 1e-5f);
      if (valid) {
        o0 = f2bf((v.x - mu)*rs*gl.x + bl.x);
        o1 = f2bf((v.y - mu)*rs*gl.y + bl.y);
      }
    }
    xnt[(2*lane  )*66 + jj] = o0;
    xnt[(2*lane+1)*66 + jj] = o1;
  }
  __syncthreads();

  // MFMA token mix: wave = head
  short8 bf_[2][2];
  #pragma unroll
  for (int nt = 0; nt < 2; nt++)
    #pragma unroll
    for (int ks = 0; ks < 2; ks++)
      bf_[nt][ks] = ld_frag(&xnt[(hd*32 + nt*16 + ln)*66 + ks*32 + qd*8]);
  floatx4 acc[4][2];
  #pragma unroll
  for (int mt = 0; mt < 4; mt++)
    #pragma unroll
    for (int nt = 0; nt < 2; nt++)
      acc[mt][nt] = (floatx4){0.f,0.f,0.f,0.f};
  #pragma unroll
  for (int ks = 0; ks < 2; ks++)
    #pragma unroll
    for (int mt = 0; mt < 4; mt++)
      #pragma unroll
      for (int nt = 0; nt < 2; nt++)
        acc[mt][nt] = __builtin_amdgcn_mfma_f32_16x16x32_bf16(af[mt][ks], bf_[nt][ks], acc[mt][nt], 0, 0, 0);

  // epilogue: residual add + spatial bias (global, L2-hot) + write
  #pragma unroll
  for (int mt = 0; mt < 4; mt++) {
    #pragma unroll
    for (int r = 0; r < 4; r++) {
      int i = mt*16 + qd*4 + r;
      if (i < WS2) {
        int ir = i / 7, ic = i - ir*7;
        int orow = wh*7 + ir - PAD, ocol = wwn*7 + ic - PAD;
        if (orow>=0 && orow<HH && ocol>=0 && ocol<WW_) {
          float sbv = sb[hd*WS2 + i];
          size_t base = ((size_t)((b*HH + orow)*WW_ + ocol))*CC + hd*32;
          #pragma unroll
          for (int nt = 0; nt < 2; nt++) {
            int c = nt*16 + ln;
            x2[base + c] = x[base + c] + acc[mt][nt][r] + sbv;
          }
        }
      }
    }
  }
}

// ---------------------------------------------------------------------------
// mlp (round-0 PROVEN baseline body, 240 us): x2 -> LN2 -> fc1+GELU -> fc2
// -> +x2. 128 tokens / 4 waves; wave = 32 rows. A-frags in VGPRs; A-LDS
// phase unioned with B1/B2/Ht (56.8 KB -> 2 blocks/CU). Weight staging
// register-prefetched one chunk ahead. Ht XOR-swizzled. Only deltas vs
// round-0: float2 LN2 and rcp-GELU (both validated in v5-v7).
// ---------------------------------------------------------------------------
__global__ __launch_bounds__(256, 2) void mlp_k(
    float* __restrict__ xio,
    const float* __restrict__ g2, const float* __restrict__ b2,
    const u16* __restrict__ fc1_wT, const float* __restrict__ fc1_b,
    const u16* __restrict__ fc2_wT, const float* __restrict__ fc2_b)
{
  // phase A: ALn u16[128][136] (34816 B)
  // phase B: B1 u16[64][136] @0 (17408) | B2 u16[128][72] @17408 (18432)
  //          | Ht u16[4][32][72] @35840 (18432)  -> union = 54272 B
  __shared__ __align__(16) char um[54272];
  __shared__ float sF1[HID];
  __shared__ float sF2[CC];
  u16* ALn = (u16*)um;
  u16* B1p = (u16*)um;
  u16* B2p = (u16*)(um + 17408);
  int tid = threadIdx.x;
  int wvid = tid >> 6, lane = tid & 63;
  int ln = lane & 15, qd = lane >> 4;
  int m0 = wvid*32;
  size_t tokbase = (size_t)blockIdx.x * 128;
  u16* Htp = (u16*)(um + 35840) + wvid*(32*72);

  sF1[tid] = fc1_b[tid]; sF1[tid+256] = fc1_b[tid+256];
  if (tid < CC) sF2[tid] = fc2_b[tid];

  // LN2 into A (128 tokens), float2-vectorized
  float2 gl = *(const float2*)&g2[2*lane];
  float2 bl = *(const float2*)&b2[2*lane];
  for (int t = wvid; t < 128; t += 4) {
    float2 v = *(const float2*)(xio + (tokbase + t)*CC + 2*lane);
    float s = v.x + v.y, ss = v.x*v.x + v.y*v.y;
    #pragma unroll
    for (int o = 32; o > 0; o >>= 1) { s += __shfl_xor(s,o); ss += __shfl_xor(ss,o); }
    float mu = s*(1.f/128.f), var = ss*(1.f/128.f) - mu*mu;
    float rs = rsqrtf(var + 1e-5f);
    *(unsigned*)&ALn[t*136 + 2*lane] =
        pk2((v.x-mu)*rs*gl.x + bl.x, (v.y-mu)*rs*gl.y + bl.y);
  }
  __syncthreads();

  // A-fragments to VGPRs (A-LDS dead afterwards)
  short8 av1[2][4];
  #pragma unroll
  for (int mt = 0; mt < 2; mt++)
    #pragma unroll
    for (int ks = 0; ks < 4; ks++)
      av1[mt][ks] = ld_frag(&ALn[(m0 + mt*16 + ln)*136 + ks*32 + qd*8]);
  __syncthreads();

  // weight staging machinery (register prefetch)
  const uint4* src1 = (const uint4*)fc1_wT;   // row = 128 u16 = 16 uint4
  const uint4* src2 = (const uint4*)fc2_wT;   // row = 512 u16 = 64 uint4
  uint4 p1[4], p2[4];
  int n1[4], q1[4], n2[4], q2[4];
  #pragma unroll
  for (int r = 0; r < 4; r++) {
    int idx = tid + r*256;
    n1[r] = idx >> 4; q1[r] = idx & 15;
    n2[r] = idx >> 3; q2[r] = idx & 7;
  }
  auto load_ch = [&](int cc){
    #pragma unroll
    for (int r = 0; r < 4; r++) {
      p1[r] = src1[(cc*64 + n1[r])*16 + q1[r]];
      p2[r] = src2[n2[r]*64 + cc*8 + q2[r]];
    }
  };
  auto store_ch = [&](){
    uint4* d1 = (uint4*)B1p; uint4* d2 = (uint4*)B2p;
    #pragma unroll
    for (int r = 0; r < 4; r++) {
      d1[n1[r]*17 + q1[r]] = p1[r];   // 136 u16 = 17 uint4
      d2[n2[r]*9  + q2[r]] = p2[r];   // 72 u16 = 9 uint4
    }
  };

  load_ch(0); store_ch();
  __syncthreads();

  floatx4 oacc[2][8];
  #pragma unroll
  for (int mt = 0; mt < 2; mt++)
    #pragma unroll
    for (int nt = 0; nt < 8; nt++) oacc[mt][nt] = (floatx4){0.f,0.f,0.f,0.f};

  for (int ch = 0; ch < 8; ch++) {
    if (ch < 7) load_ch(ch+1);   // prefetch next chunk into VGPRs

    // gemm1: h[32 x 64] = A-rows @ B1^T
    floatx4 h[2][4];
    #pragma unroll
    for (int mt = 0; mt < 2; mt++)
      #pragma unroll
      for (int nt = 0; nt < 4; nt++) h[mt][nt] = (floatx4){0.f,0.f,0.f,0.f};
    #pragma unroll
    for (int nt = 0; nt < 4; nt++) {
      short8 bv[4];
      #pragma unroll
      for (int ks = 0; ks < 4; ks++)
        bv[ks] = ld_frag(&B1p[(nt*16 + ln)*136 + ks*32 + qd*8]);
      #pragma unroll
      for (int mt = 0; mt < 2; mt++)
        #pragma unroll
        for (int ks = 0; ks < 4; ks++)
          h[mt][nt] = __builtin_amdgcn_mfma_f32_16x16x32_bf16(av1[mt][ks], bv[ks], h[mt][nt], 0, 0, 0);
    }
    // bias + GELU -> Ht (per-wave region, XOR-swizzled, D->A layout)
    #pragma unroll
    for (int mt = 0; mt < 2; mt++)
      #pragma unroll
      for (int nt = 0; nt < 4; nt++) {
        float bias = sF1[ch*64 + nt*16 + ln];
        #pragma unroll
        for (int r = 0; r < 4; r++) {
          float g = gelu_f(h[mt][nt][r] + bias);
          int row = mt*16 + qd*4 + r;
          int col = nt*16 + ln;
          Htp[row*72 + (col ^ ((row & 8) << 1))] = f2bf(g);
        }
      }
    asm volatile("s_waitcnt lgkmcnt(0)" ::: "memory");  // same-wave Ht handoff

    // gemm2: oacc[32 x 128] += Ht @ B2^T
    short8 av2[2][2];
    #pragma unroll
    for (int mt = 0; mt < 2; mt++)
      #pragma unroll
      for (int ks = 0; ks < 2; ks++) {
        int rrow = mt*16 + ln;
        int kk = ks*32 + qd*8;
        av2[mt][ks] = ld_frag(&Htp[rrow*72 + (kk ^ ((rrow & 8) << 1))]);
      }
    #pragma unroll
    for (int nt = 0; nt < 8; nt++) {
      short8 bv2[2];
      #pragma unroll
      for (int ks = 0; ks < 2; ks++)
        bv2[ks] = ld_frag(&B2p[(nt*16 + ln)*72 + ks*32 + qd*8]);
      #pragma unroll
      for (int mt = 0; mt < 2; mt++)
        #pragma unroll
        for (int ks = 0; ks < 2; ks++)
          oacc[mt][nt] = __builtin_amdgcn_mfma_f32_16x16x32_bf16(av2[mt][ks], bv2[ks], oacc[mt][nt], 0, 0, 0);
    }
    __syncthreads();             // all waves done reading B1/B2
    if (ch < 7) { store_ch(); __syncthreads(); }
  }

  // epilogue: + fc2 bias + residual, in-place
  #pragma unroll
  for (int mt = 0; mt < 2; mt++)
    #pragma unroll
    for (int r = 0; r < 4; r++) {
      size_t tok = tokbase + m0 + mt*16 + qd*4 + r;
      float* rowp = xio + tok*CC;
      #pragma unroll
      for (int nt = 0; nt < 8; nt++) {
        int n = nt*16 + ln;
        rowp[n] = rowp[n] + oacc[mt][nt][r] + sF2[n];
      }
    }
}

extern "C" void kernel_launch(void* const* d_in, const int* in_sizes, int n_in,
                              void* d_out, int out_size, void* d_ws, size_t ws_size,
                              hipStream_t stream) {
  const float* x     = (const float*)d_in[0];
  const float* g1    = (const float*)d_in[1];
  const float* b1    = (const float*)d_in[2];
  const float* sw    = (const float*)d_in[3];
  const float* sb    = (const float*)d_in[4];
  const float* g2    = (const float*)d_in[5];
  const float* b2    = (const float*)d_in[6];
  const float* fc1_w = (const float*)d_in[7];
  const float* fc1_b = (const float*)d_in[8];
  const float* fc2_w = (const float*)d_in[9];
  const float* fc2_b = (const float*)d_in[10];
  float* out = (float*)d_out;

  u16* fc1_wT = (u16*)d_ws;                  // 512*128 bf16 (131072 B)
  u16* fc2_wT = fc1_wT + HID*CC;             // 128*512 bf16 (131072 B)
  u16* swT    = fc2_wT + CC*HID;             // 4*64*80 bf16 (40960 B)

  prep_k<<<64, 256, 0, stream>>>(fc1_w, fc2_w, sw, fc1_wT, fc2_wT, swT);
  winmix_k<<<NB*81, 256, 0, stream>>>(x, g1, b1, swT, sb, out);
  mlp_k<<<(NB*HH*WW_)/128, 256, 0, stream>>>(out, g2, b2, fc1_wT, fc1_b, fc2_wT, fc2_b);
}

// Round 9
// 419.120 us; speedup vs baseline: 1.2687x; 1.0972x over previous
//
#include <hip/hip_runtime.h>

typedef unsigned short u16;
typedef __attribute__((ext_vector_type(8))) short short8;
typedef __attribute__((ext_vector_type(4))) float floatx4;

#define NB 64
#define HH 56
#define WW_ 56
#define CC 128
#define NHEADS 4
#define WS2 49
#define PAD 4      // P_T = P_L = 4
#define HID 512

__device__ __forceinline__ float bf2f(u16 u){ return __uint_as_float(((unsigned)u)<<16); }
__device__ __forceinline__ u16 f2bf(float f){
  unsigned u = __float_as_uint(f);
  return (u16)((u + 0x7FFFu + ((u>>16)&1u)) >> 16);
}
// pack two f32 -> one u32 of 2 bf16 (lo = a, hi = b)
__device__ __forceinline__ unsigned pk2(float a, float b){
  return ((unsigned)f2bf(b) << 16) | (unsigned)f2bf(a);
}
// tanh-approx GELU, sigmoid form, approx rcp (validated, absmax unchanged)
__device__ __forceinline__ float gelu_f(float x){
  float u2 = x*(1.5957691216f + 0.0713548162f*x*x);
  return x * __builtin_amdgcn_rcpf(1.f + __expf(-u2));
}
// element-wise fragment load (LDS); compiler merges to widest aligned DS op
__device__ __forceinline__ short8 ld_frag(const u16* p){
  short8 v;
  #pragma unroll
  for (int e = 0; e < 8; e++) v[e] = (short)p[e];
  return v;
}
// vector fragment load (global, 16B-aligned)
__device__ __forceinline__ short8 ld_frag_g(const u16* p){
  return *(const short8*)p;
}

// ---------------------------------------------------------------------------
// prep: fc1_w (C,HID) f32 -> bf16 [HID][C];  fc2_w (HID,C) f32 -> bf16 [C][HID]
//       spatial_w [h][i][j] f32 -> bf16 [h][i(64)][j(stride 80)], zero-padded
// ---------------------------------------------------------------------------
__global__ __launch_bounds__(256) void prep_k(
    const float* __restrict__ fc1_w, const float* __restrict__ fc2_w,
    const float* __restrict__ sw,
    u16* __restrict__ fc1_wT, u16* __restrict__ fc2_wT, u16* __restrict__ swT)
{
  int tid = blockIdx.x*256 + threadIdx.x;
  int nth = gridDim.x * 256;
  for (int idx = tid; idx < HID*CC; idx += nth) {
    int n = idx >> 7, k = idx & 127;
    fc1_wT[idx] = f2bf(fc1_w[k*HID + n]);
  }
  for (int idx = tid; idx < CC*HID; idx += nth) {
    int c = idx >> 9, h = idx & 511;
    fc2_wT[idx] = f2bf(fc2_w[h*CC + c]);
  }
  for (int idx = tid; idx < NHEADS*64*80; idx += nth) {
    int hd = idx / (64*80); int rem = idx - hd*64*80;
    int i = rem / 80, j = rem - i*80;
    swT[idx] = (i < WS2 && j < WS2) ? f2bf(sw[(hd*WS2 + i)*WS2 + j]) : (u16)0;
  }
}

// ---------------------------------------------------------------------------
// winmix v4: fused LN1 + window token mix + residual -> x2
// one block per (batch, window); wave = head. W direct from global (L2-hot).
// LN loop restructured to STATIC trip count (it*4+wvid) with unconditional
// clamped loads -> compiler can unroll & batch the 16 independent global
// loads (was: runtime lower bound -> 16 serial latency rounds).
// ---------------------------------------------------------------------------
__global__ __launch_bounds__(256, 4) void winmix_k(
    const float* __restrict__ x, const float* __restrict__ g1, const float* __restrict__ b1,
    const u16* __restrict__ swT, const float* __restrict__ sb,
    float* __restrict__ x2)
{
  __shared__ u16 xnt[CC*66];         // 16896 B, bf16 LN-out [c][j] stride 66
  int tid = threadIdx.x;
  int wvid = tid >> 6, lane = tid & 63;
  int ln = lane & 15, qd = lane >> 4;
  int b = blockIdx.x / 81; int wi = blockIdx.x - b*81;
  int wh = wi / 9, wwn = wi - wh*9;
  int hd = wvid;

  // W A-frags straight from global (L2-hot); no deps -> hoisted under LN
  short8 af[4][2];
  #pragma unroll
  for (int mt = 0; mt < 4; mt++)
    #pragma unroll
    for (int ks = 0; ks < 2; ks++)
      af[mt][ks] = ld_frag_g(&swT[(size_t)(hd*64 + mt*16 + ln)*80 + ks*32 + qd*8]);

  // LN per window position (transposed write); static-trip, clamped loads
  float2 gl = *(const float2*)&g1[2*lane];
  float2 bl = *(const float2*)&b1[2*lane];
  #pragma unroll 8
  for (int it = 0; it < 16; ++it) {
    int jj = it*4 + wvid;
    int jr = jj / 7, jc = jj - jr*7;
    int pr = wh*7 + jr - PAD, pc = wwn*7 + jc - PAD;
    bool valid = (jj < WS2) & (pr>=0) & (pr<HH) & (pc>=0) & (pc<WW_);
    int prc = min(max(pr, 0), HH-1), pcc = min(max(pc, 0), WW_-1);
    const float* px = x + ((size_t)((b*HH + prc)*WW_ + pcc))*CC;
    float2 v = *(const float2*)(px + 2*lane);   // unconditional -> hoistable
    if (!valid) { v.x = 0.f; v.y = 0.f; }
    float s = v.x + v.y, ss = v.x*v.x + v.y*v.y;
    #pragma unroll
    for (int o = 32; o > 0; o >>= 1) { s += __shfl_xor(s, o); ss += __shfl_xor(ss, o); }
    float mu = s * (1.f/128.f);
    float var = ss * (1.f/128.f) - mu*mu;
    float rs = rsqrtf(var + 1e-5f);
    u16 o0 = 0, o1 = 0;
    if (valid) {
      o0 = f2bf((v.x - mu)*rs*gl.x + bl.x);
      o1 = f2bf((v.y - mu)*rs*gl.y + bl.y);
    }
    xnt[(2*lane  )*66 + jj] = o0;
    xnt[(2*lane+1)*66 + jj] = o1;
  }
  __syncthreads();

  // MFMA token mix: wave = head
  short8 bf_[2][2];
  #pragma unroll
  for (int nt = 0; nt < 2; nt++)
    #pragma unroll
    for (int ks = 0; ks < 2; ks++)
      bf_[nt][ks] = ld_frag(&xnt[(hd*32 + nt*16 + ln)*66 + ks*32 + qd*8]);
  floatx4 acc[4][2];
  #pragma unroll
  for (int mt = 0; mt < 4; mt++)
    #pragma unroll
    for (int nt = 0; nt < 2; nt++)
      acc[mt][nt] = (floatx4){0.f,0.f,0.f,0.f};
  #pragma unroll
  for (int ks = 0; ks < 2; ks++)
    #pragma unroll
    for (int mt = 0; mt < 4; mt++)
      #pragma unroll
      for (int nt = 0; nt < 2; nt++)
        acc[mt][nt] = __builtin_amdgcn_mfma_f32_16x16x32_bf16(af[mt][ks], bf_[nt][ks], acc[mt][nt], 0, 0, 0);

  // epilogue: residual add + spatial bias (global, L2-hot) + write
  #pragma unroll
  for (int mt = 0; mt < 4; mt++) {
    #pragma unroll
    for (int r = 0; r < 4; r++) {
      int i = mt*16 + qd*4 + r;
      if (i < WS2) {
        int ir = i / 7, ic = i - ir*7;
        int orow = wh*7 + ir - PAD, ocol = wwn*7 + ic - PAD;
        if (orow>=0 && orow<HH && ocol>=0 && ocol<WW_) {
          float sbv = sb[hd*WS2 + i];
          size_t base = ((size_t)((b*HH + orow)*WW_ + ocol))*CC + hd*32;
          #pragma unroll
          for (int nt = 0; nt < 2; nt++) {
            int c = nt*16 + ln;
            x2[base + c] = x[base + c] + acc[mt][nt][r] + sbv;
          }
        }
      }
    }
  }
}

// ---------------------------------------------------------------------------
// mlp (round-7 proven body, 232 us). Deltas this round:
//  - LN2 loop static-trip (it*4+wvid), unroll 8 -> batched global loads.
//  - per-chunk asm lgkmcnt "memory" barrier REMOVED: same-wave DS alias
//    ordering covers the Ht handoff (proven v3/v4); compiler-counted
//    lgkmcnt <= full drain, scheduler regains freedom.
// Everything else byte-identical (XOR-swizzled Ht, LDS biases, (256,2)).
// ---------------------------------------------------------------------------
__global__ __launch_bounds__(256, 2) void mlp_k(
    float* __restrict__ xio,
    const float* __restrict__ g2, const float* __restrict__ b2,
    const u16* __restrict__ fc1_wT, const float* __restrict__ fc1_b,
    const u16* __restrict__ fc2_wT, const float* __restrict__ fc2_b)
{
  // phase A: ALn u16[128][136] (34816 B)
  // phase B: B1 u16[64][136] @0 (17408) | B2 u16[128][72] @17408 (18432)
  //          | Ht u16[4][32][72] @35840 (18432)  -> union = 54272 B
  __shared__ __align__(16) char um[54272];
  __shared__ float sF1[HID];
  __shared__ float sF2[CC];
  u16* ALn = (u16*)um;
  u16* B1p = (u16*)um;
  u16* B2p = (u16*)(um + 17408);
  int tid = threadIdx.x;
  int wvid = tid >> 6, lane = tid & 63;
  int ln = lane & 15, qd = lane >> 4;
  int m0 = wvid*32;
  size_t tokbase = (size_t)blockIdx.x * 128;
  u16* Htp = (u16*)(um + 35840) + wvid*(32*72);

  sF1[tid] = fc1_b[tid]; sF1[tid+256] = fc1_b[tid+256];
  if (tid < CC) sF2[tid] = fc2_b[tid];

  // LN2 into A (128 tokens), float2-vectorized, static-trip unrolled
  float2 gl = *(const float2*)&g2[2*lane];
  float2 bl = *(const float2*)&b2[2*lane];
  #pragma unroll 8
  for (int it = 0; it < 32; ++it) {
    int t = it*4 + wvid;
    float2 v = *(const float2*)(xio + (tokbase + t)*CC + 2*lane);
    float s = v.x + v.y, ss = v.x*v.x + v.y*v.y;
    #pragma unroll
    for (int o = 32; o > 0; o >>= 1) { s += __shfl_xor(s,o); ss += __shfl_xor(ss,o); }
    float mu = s*(1.f/128.f), var = ss*(1.f/128.f) - mu*mu;
    float rs = rsqrtf(var + 1e-5f);
    *(unsigned*)&ALn[t*136 + 2*lane] =
        pk2((v.x-mu)*rs*gl.x + bl.x, (v.y-mu)*rs*gl.y + bl.y);
  }
  __syncthreads();

  // A-fragments to VGPRs (A-LDS dead afterwards)
  short8 av1[2][4];
  #pragma unroll
  for (int mt = 0; mt < 2; mt++)
    #pragma unroll
    for (int ks = 0; ks < 4; ks++)
      av1[mt][ks] = ld_frag(&ALn[(m0 + mt*16 + ln)*136 + ks*32 + qd*8]);
  __syncthreads();

  // weight staging machinery (register prefetch)
  const uint4* src1 = (const uint4*)fc1_wT;   // row = 128 u16 = 16 uint4
  const uint4* src2 = (const uint4*)fc2_wT;   // row = 512 u16 = 64 uint4
  uint4 p1[4], p2[4];
  int n1[4], q1[4], n2[4], q2[4];
  #pragma unroll
  for (int r = 0; r < 4; r++) {
    int idx = tid + r*256;
    n1[r] = idx >> 4; q1[r] = idx & 15;
    n2[r] = idx >> 3; q2[r] = idx & 7;
  }
  auto load_ch = [&](int cc){
    #pragma unroll
    for (int r = 0; r < 4; r++) {
      p1[r] = src1[(cc*64 + n1[r])*16 + q1[r]];
      p2[r] = src2[n2[r]*64 + cc*8 + q2[r]];
    }
  };
  auto store_ch = [&](){
    uint4* d1 = (uint4*)B1p; uint4* d2 = (uint4*)B2p;
    #pragma unroll
    for (int r = 0; r < 4; r++) {
      d1[n1[r]*17 + q1[r]] = p1[r];   // 136 u16 = 17 uint4
      d2[n2[r]*9  + q2[r]] = p2[r];   // 72 u16 = 9 uint4
    }
  };

  load_ch(0); store_ch();
  __syncthreads();

  floatx4 oacc[2][8];
  #pragma unroll
  for (int mt = 0; mt < 2; mt++)
    #pragma unroll
    for (int nt = 0; nt < 8; nt++) oacc[mt][nt] = (floatx4){0.f,0.f,0.f,0.f};

  for (int ch = 0; ch < 8; ch++) {
    if (ch < 7) load_ch(ch+1);   // prefetch next chunk into VGPRs

    // gemm1: h[32 x 64] = A-rows @ B1^T
    floatx4 h[2][4];
    #pragma unroll
    for (int mt = 0; mt < 2; mt++)
      #pragma unroll
      for (int nt = 0; nt < 4; nt++) h[mt][nt] = (floatx4){0.f,0.f,0.f,0.f};
    #pragma unroll
    for (int nt = 0; nt < 4; nt++) {
      short8 bv[4];
      #pragma unroll
      for (int ks = 0; ks < 4; ks++)
        bv[ks] = ld_frag(&B1p[(nt*16 + ln)*136 + ks*32 + qd*8]);
      #pragma unroll
      for (int mt = 0; mt < 2; mt++)
        #pragma unroll
        for (int ks = 0; ks < 4; ks++)
          h[mt][nt] = __builtin_amdgcn_mfma_f32_16x16x32_bf16(av1[mt][ks], bv[ks], h[mt][nt], 0, 0, 0);
    }
    // bias + GELU -> Ht (per-wave region, XOR-swizzled, D->A layout)
    #pragma unroll
    for (int mt = 0; mt < 2; mt++)
      #pragma unroll
      for (int nt = 0; nt < 4; nt++) {
        float bias = sF1[ch*64 + nt*16 + ln];
        #pragma unroll
        for (int r = 0; r < 4; r++) {
          float g = gelu_f(h[mt][nt][r] + bias);
          int row = mt*16 + qd*4 + r;
          int col = nt*16 + ln;
          Htp[row*72 + (col ^ ((row & 8) << 1))] = f2bf(g);
        }
      }
    // same-wave DS in-order + compiler alias ordering: no asm barrier needed

    // gemm2: oacc[32 x 128] += Ht @ B2^T
    short8 av2[2][2];
    #pragma unroll
    for (int mt = 0; mt < 2; mt++)
      #pragma unroll
      for (int ks = 0; ks < 2; ks++) {
        int rrow = mt*16 + ln;
        int kk = ks*32 + qd*8;
        av2[mt][ks] = ld_frag(&Htp[rrow*72 + (kk ^ ((rrow & 8) << 1))]);
      }
    #pragma unroll
    for (int nt = 0; nt < 8; nt++) {
      short8 bv2[2];
      #pragma unroll
      for (int ks = 0; ks < 2; ks++)
        bv2[ks] = ld_frag(&B2p[(nt*16 + ln)*72 + ks*32 + qd*8]);
      #pragma unroll
      for (int mt = 0; mt < 2; mt++)
        #pragma unroll
        for (int ks = 0; ks < 2; ks++)
          oacc[mt][nt] = __builtin_amdgcn_mfma_f32_16x16x32_bf16(av2[mt][ks], bv2[ks], oacc[mt][nt], 0, 0, 0);
    }
    __syncthreads();             // all waves done reading B1/B2
    if (ch < 7) { store_ch(); __syncthreads(); }
  }

  // epilogue: + fc2 bias + residual, in-place
  #pragma unroll
  for (int mt = 0; mt < 2; mt++)
    #pragma unroll
    for (int r = 0; r < 4; r++) {
      size_t tok = tokbase + m0 + mt*16 + qd*4 + r;
      float* rowp = xio + tok*CC;
      #pragma unroll
      for (int nt = 0; nt < 8; nt++) {
        int n = nt*16 + ln;
        rowp[n] = rowp[n] + oacc[mt][nt][r] + sF2[n];
      }
    }
}

extern "C" void kernel_launch(void* const* d_in, const int* in_sizes, int n_in,
                              void* d_out, int out_size, void* d_ws, size_t ws_size,
                              hipStream_t stream) {
  const float* x     = (const float*)d_in[0];
  const float* g1    = (const float*)d_in[1];
  const float* b1    = (const float*)d_in[2];
  const float* sw    = (const float*)d_in[3];
  const float* sb    = (const float*)d_in[4];
  const float* g2    = (const float*)d_in[5];
  const float* b2    = (const float*)d_in[6];
  const float* fc1_w = (const float*)d_in[7];
  const float* fc1_b = (const float*)d_in[8];
  const float* fc2_w = (const float*)d_in[9];
  const float* fc2_b = (const float*)d_in[10];
  float* out = (float*)d_out;

  u16* fc1_wT = (u16*)d_ws;                  // 512*128 bf16 (131072 B)
  u16* fc2_wT = fc1_wT + HID*CC;             // 128*512 bf16 (131072 B)
  u16* swT    = fc2_wT + CC*HID;             // 4*64*80 bf16 (40960 B)

  prep_k<<<128, 256, 0, stream>>>(fc1_w, fc2_w, sw, fc1_wT, fc2_wT, swT);
  winmix_k<<<NB*81, 256, 0, stream>>>(x, g1, b1, swT, sb, out);
  mlp_k<<<(NB*HH*WW_)/128, 256, 0, stream>>>(out, g2, b2, fc1_wT, fc1_b, fc2_wT, fc2_b);
}